// Round 1
// baseline (336.140 us; speedup 1.0000x reference)
//
#include <hip/hip_runtime.h>
#include <hip/hip_bf16.h>
#include <math.h>

#define HH 496
#define WW 432
#define CC 64
#define BB 2
#define NN 8192
#define HW_ (HH * WW)

typedef __attribute__((ext_vector_type(8))) short bhalf8;
typedef __attribute__((ext_vector_type(4))) float f32x4;

__device__ __forceinline__ unsigned short f2bf(float f) {
  union { float f; unsigned int u; } v; v.f = f;
  unsigned int r = (v.u + 0x7fffu + ((v.u >> 16) & 1u)) >> 16;
  return (unsigned short)r;
}

// ---------------- zero the (B,C,H,W) output ----------------
__global__ void zero_kernel(float4* __restrict__ out, int n4) {
  int i = blockIdx.x * blockDim.x + threadIdx.x;
  int stride = gridDim.x * blockDim.x;
  float4 z = make_float4(0.f, 0.f, 0.f, 0.f);
  for (; i < n4; i += stride) out[i] = z;
}

// ---------------- sin/cos tables + weight transposes ----------------
__global__ void prep_kernel(float* __restrict__ tabHS, float* __restrict__ tabHC,
                            float* __restrict__ tabWS, float* __restrict__ tabWC,
                            const float* __restrict__ qw, const float* __restrict__ kw,
                            const float* __restrict__ vw, const float* __restrict__ w1,
                            const float* __restrict__ w2, float* __restrict__ wT) {
  int tid = blockIdx.x * blockDim.x + threadIdx.x;
  const int ntab = (HH + WW) * 32;
  if (tid < ntab) {
    int j = tid & 31;
    // theta_j = 10000^(-j/32) = exp(-j*ln(10000)/32)
    float theta = __expf(-(float)j * (9.210340371976184f / 32.f));
    if (tid < HH * 32) {
      int i = tid >> 5;
      float h = -1.f + 2.f * (float)i / (float)(HH - 1);
      float a = h * theta;
      tabHS[tid] = sinf(a);
      tabHC[tid] = cosf(a);
    } else {
      int t2 = tid - HH * 32;
      int i = t2 >> 5;
      float w = -1.f + 2.f * (float)i / (float)(WW - 1);
      float a = w * theta;
      tabWS[t2] = sinf(a);
      tabWC[t2] = cosf(a);
    }
  } else if (tid < ntab + 5 * 4096) {
    int t = tid - ntab;
    int mm = t >> 12, r = t & 4095, k = r >> 6, ch = r & 63;
    const float* src = mm == 0 ? qw : mm == 1 ? kw : mm == 2 ? vw : mm == 3 ? w1 : w2;
    wT[t] = src[ch * 64 + k];  // wT[m][k][c] = w_m[c][k]
  }
}

// ---------------- gather + RoPE + LN1 + QKV projection ----------------
// one wave per point, lane = channel
__global__ __launch_bounds__(256) void qkv_kernel(
    const float* __restrict__ pillar, const int* __restrict__ vidx,
    const float* __restrict__ tabHS, const float* __restrict__ tabHC,
    const float* __restrict__ tabWS, const float* __restrict__ tabWC,
    const float* __restrict__ wT,
    const float* __restrict__ qb, const float* __restrict__ kbias,
    const float* __restrict__ vb,
    const float* __restrict__ n1g, const float* __restrict__ n1b,
    float* __restrict__ g_out, unsigned short* __restrict__ Qb,
    unsigned short* __restrict__ Kb, unsigned short* __restrict__ Vt) {
  int wid = threadIdx.x >> 6, lane = threadIdx.x & 63;
  int pt = blockIdx.x * 4 + wid;  // 0 .. B*N-1
  int c = lane;
  size_t base = (size_t)pt * CC;
  float x = pillar[base + c];
  int pos = vidx[pt];
  int h = pos / WW;
  int w = pos - h * WW;
  int j = c & 31;
  float x1 = __shfl(x, j);
  float x2 = __shfl(x, j + 32);
  float hs = tabHS[h * 32 + j], hc = tabHC[h * 32 + j];
  float ws = tabWS[w * 32 + j], wc = tabWC[w * 32 + j];
  float rope = (c < 32) ? (x1 * hc * wc - x2 * hs * ws)
                        : (x1 * hs * ws + x2 * hc * wc);
  float gv = x + rope;
  g_out[base + c] = gv;
  // LayerNorm over 64 channels
  float s = gv;
  for (int m = 1; m <= 32; m <<= 1) s += __shfl_xor(s, m);
  float mean = s * (1.f / 64.f);
  float d = gv - mean;
  float vs = d * d;
  for (int m = 1; m <= 32; m <<= 1) vs += __shfl_xor(vs, m);
  float rstd = rsqrtf(vs * (1.f / 64.f) + 1e-5f);
  float gn = d * rstd * n1g[c] + n1b[c];
  // Q,K,V matvecs (weights transposed: coalesced across lanes)
  const float* qwT = wT;
  const float* kwT = wT + 4096;
  const float* vwT = wT + 8192;
  float q = qb[c], k = kbias[c], v = vb[c];
#pragma unroll 16
  for (int kk = 0; kk < 64; kk++) {
    float gk = __shfl(gn, kk);
    q = fmaf(gk, qwT[kk * 64 + c], q);
    k = fmaf(gk, kwT[kk * 64 + c], k);
    v = fmaf(gk, vwT[kk * 64 + c], v);
  }
  Qb[base + c] = f2bf(q);
  Kb[base + c] = f2bf(k);
  int bb = pt >> 13;          // /NN
  int nn = pt & (NN - 1);
  Vt[((size_t)bb * CC + c) * NN + nn] = f2bf(v);  // V transposed [c][n]
}

// ---------------- flash attention, 16 q-rows per wave ----------------
__global__ __launch_bounds__(256) void attn_kernel(
    const unsigned short* __restrict__ Qb, const unsigned short* __restrict__ Kb,
    const unsigned short* __restrict__ Vt, const float* __restrict__ g_in,
    float* __restrict__ att) {
  __shared__ unsigned short Plds[4][16][40];  // padded rows (80B) -> only 2-way bank alias
  int wid = threadIdx.x >> 6, lane = threadIdx.x & 63;
  int l16 = lane & 15, lg = lane >> 4;
  int blk = blockIdx.x;
  int b = blk >> 7;      // 128 tiles per batch
  int tile = blk & 127;
  int q0 = tile * 64 + wid * 16;
  const unsigned short* Q = Qb + (size_t)b * NN * CC;
  const unsigned short* K = Kb + (size_t)b * NN * CC;
  const unsigned short* V = Vt + (size_t)b * CC * NN;

  // Q fragments: A-layout lane -> row q0+l16, k = lg*8..+7 (plus k+32)
  bhalf8 aQ0 = *(const bhalf8*)(Q + (size_t)(q0 + l16) * CC + lg * 8);
  bhalf8 aQ1 = *(const bhalf8*)(Q + (size_t)(q0 + l16) * CC + 32 + lg * 8);

  f32x4 acc[4];
#pragma unroll
  for (int i = 0; i < 4; i++) acc[i] = (f32x4){0.f, 0.f, 0.f, 0.f};
  float m[4], L[4];
#pragma unroll
  for (int r = 0; r < 4; r++) { m[r] = -1e30f; L[r] = 0.f; }

  for (int kv0 = 0; kv0 < NN; kv0 += 32) {
    f32x4 S[2];
#pragma unroll
    for (int hh = 0; hh < 2; hh++) {
      const unsigned short* Kr = K + (size_t)(kv0 + 16 * hh + l16) * CC + lg * 8;
      bhalf8 bK0 = *(const bhalf8*)(Kr);
      bhalf8 bK1 = *(const bhalf8*)(Kr + 32);
      f32x4 sa = (f32x4){0.f, 0.f, 0.f, 0.f};
      sa = __builtin_amdgcn_mfma_f32_16x16x32_bf16(aQ0, bK0, sa, 0, 0, 0);
      sa = __builtin_amdgcn_mfma_f32_16x16x32_bf16(aQ1, bK1, sa, 0, 0, 0);
      S[hh] = sa;
    }
    // online softmax: rows = q0 + lg*4 + r
    float pm[4], ps[4], sc[4];
#pragma unroll
    for (int r = 0; r < 4; r++) pm[r] = fmaxf(S[0][r], S[1][r]);
#pragma unroll
    for (int msk = 1; msk <= 8; msk <<= 1) {
#pragma unroll
      for (int r = 0; r < 4; r++) pm[r] = fmaxf(pm[r], __shfl_xor(pm[r], msk));
    }
#pragma unroll
    for (int r = 0; r < 4; r++) {
      float mn = fmaxf(m[r], pm[r]);
      sc[r] = __expf(m[r] - mn);
      m[r] = mn;
      float p0 = __expf(S[0][r] - mn);
      float p1 = __expf(S[1][r] - mn);
      S[0][r] = p0; S[1][r] = p1;
      ps[r] = p0 + p1;
    }
#pragma unroll
    for (int msk = 1; msk <= 8; msk <<= 1) {
#pragma unroll
      for (int r = 0; r < 4; r++) ps[r] += __shfl_xor(ps[r], msk);
    }
#pragma unroll
    for (int r = 0; r < 4; r++) L[r] = L[r] * sc[r] + ps[r];
#pragma unroll
    for (int cg = 0; cg < 4; cg++) {
#pragma unroll
      for (int r = 0; r < 4; r++) acc[cg][r] *= sc[r];
    }
    // D-layout -> A-layout via per-wave LDS (bf16)
#pragma unroll
    for (int hh = 0; hh < 2; hh++) {
#pragma unroll
      for (int r = 0; r < 4; r++)
        Plds[wid][lg * 4 + r][l16 + 16 * hh] = f2bf(S[hh][r]);
    }
    bhalf8 aP = *(bhalf8*)(&Plds[wid][l16][lg * 8]);
    // PV: O[q][c] += P[q][kv] * Vt[c][kv]
#pragma unroll
    for (int cg = 0; cg < 4; cg++) {
      bhalf8 bV = *(const bhalf8*)(V + (size_t)(l16 + 16 * cg) * NN + kv0 + lg * 8);
      acc[cg] = __builtin_amdgcn_mfma_f32_16x16x32_bf16(aP, bV, acc[cg], 0, 0, 0);
    }
  }
  // epilogue: normalize + residual g
#pragma unroll
  for (int r = 0; r < 4; r++) L[r] = 1.f / L[r];
#pragma unroll
  for (int cg = 0; cg < 4; cg++) {
#pragma unroll
    for (int r = 0; r < 4; r++) {
      int row = q0 + lg * 4 + r;
      size_t gi = ((size_t)b * NN + row) * CC + l16 + 16 * cg;
      att[gi] = acc[cg][r] * L[r] + g_in[gi];
    }
  }
}

// ---------------- LN2 + FFN + residual + scatter ----------------
__global__ __launch_bounds__(256) void ffn_kernel(
    const float* __restrict__ att, const int* __restrict__ vidx,
    const float* __restrict__ wT, const float* __restrict__ b1,
    const float* __restrict__ b2, const float* __restrict__ n2g,
    const float* __restrict__ n2b, float* __restrict__ out) {
  int wid = threadIdx.x >> 6, lane = threadIdx.x & 63;
  int pt = blockIdx.x * 4 + wid;
  int c = lane;
  size_t base = (size_t)pt * CC;
  float a = att[base + c];
  float s = a;
  for (int m = 1; m <= 32; m <<= 1) s += __shfl_xor(s, m);
  float mean = s * (1.f / 64.f);
  float d = a - mean;
  float vs = d * d;
  for (int m = 1; m <= 32; m <<= 1) vs += __shfl_xor(vs, m);
  float rstd = rsqrtf(vs * (1.f / 64.f) + 1e-5f);
  float t = d * rstd * n2g[c] + n2b[c];
  const float* w1T = wT + 3 * 4096;
  const float* w2T = wT + 4 * 4096;
  float h1 = b1[c];
#pragma unroll 16
  for (int kk = 0; kk < 64; kk++)
    h1 = fmaf(__shfl(t, kk), w1T[kk * 64 + c], h1);
  // exact gelu
  h1 = 0.5f * h1 * (1.f + erff(h1 * 0.70710678118654752f));
  float u = b2[c] + a;
#pragma unroll 16
  for (int kk = 0; kk < 64; kk++)
    u = fmaf(__shfl(h1, kk), w2T[kk * 64 + c], u);
  int pos = vidx[pt];
  int bb = pt >> 13;
  out[(size_t)bb * CC * HW_ + (size_t)c * HW_ + pos] = u;
}

extern "C" void kernel_launch(void* const* d_in, const int* in_sizes, int n_in,
                              void* d_out, int out_size, void* d_ws, size_t ws_size,
                              hipStream_t stream) {
  const float* pillar = (const float*)d_in[0];
  const int* vidx = (const int*)d_in[1];
  const float* qw = (const float*)d_in[2];
  const float* qb = (const float*)d_in[3];
  const float* kw = (const float*)d_in[4];
  const float* kb = (const float*)d_in[5];
  const float* vw = (const float*)d_in[6];
  const float* vb = (const float*)d_in[7];
  const float* w1 = (const float*)d_in[8];
  const float* b1 = (const float*)d_in[9];
  const float* w2 = (const float*)d_in[10];
  const float* b2 = (const float*)d_in[11];
  const float* n1g = (const float*)d_in[12];
  const float* n1b = (const float*)d_in[13];
  const float* n2g = (const float*)d_in[14];
  const float* n2b = (const float*)d_in[15];
  float* out = (float*)d_out;

  char* ws = (char*)d_ws;
  size_t off = 0;
  auto take = [&](size_t bytes) -> char* {
    off = (off + 255) & ~(size_t)255;
    char* p = ws + off;
    off += bytes;
    return p;
  };
  float* tabHS = (float*)take((size_t)HH * 32 * 4);
  float* tabHC = (float*)take((size_t)HH * 32 * 4);
  float* tabWS = (float*)take((size_t)WW * 32 * 4);
  float* tabWC = (float*)take((size_t)WW * 32 * 4);
  float* wT = (float*)take((size_t)5 * 4096 * 4);
  float* gbuf = (float*)take((size_t)BB * NN * CC * 4);
  float* attb = (float*)take((size_t)BB * NN * CC * 4);
  unsigned short* Qb = (unsigned short*)take((size_t)BB * NN * CC * 2);
  unsigned short* Kb = (unsigned short*)take((size_t)BB * NN * CC * 2);
  unsigned short* Vt = (unsigned short*)take((size_t)BB * CC * NN * 2);

  int n4 = out_size / 4;
  zero_kernel<<<2048, 256, 0, stream>>>((float4*)out, n4);
  int preptot = (HH + WW) * 32 + 5 * 4096;
  prep_kernel<<<(preptot + 255) / 256, 256, 0, stream>>>(
      tabHS, tabHC, tabWS, tabWC, qw, kw, vw, w1, w2, wT);
  qkv_kernel<<<BB * NN / 4, 256, 0, stream>>>(
      pillar, vidx, tabHS, tabHC, tabWS, tabWC, wT, qb, kb, vb, n1g, n1b,
      gbuf, Qb, Kb, Vt);
  attn_kernel<<<BB * (NN / 64), 256, 0, stream>>>(Qb, Kb, Vt, gbuf, attb);
  ffn_kernel<<<BB * NN / 4, 256, 0, stream>>>(attb, vidx, wT, b1, b2, n2g, n2b, out);
}